// Round 4
// baseline (1830.096 us; speedup 1.0000x reference)
//
#include <hip/hip_runtime.h>
#include <hip/hip_bf16.h>
#include <stdint.h>

// ---------------------------------------------------------------------------
// LoRALinear: y = x @ (W + B@A)^T + (b + lora_bias)
// M=8192, N=4096, K=4096.
// R4: gemm redesigned 512x256 tile, BK=32, 8 waves (4Mx2N), per-wave 128x128.
//  - LDS demand 62% of MFMA (was 93%) -> phases no longer LDS-serialized
//  - 64-B LDS rows: naturally conflict-free for 16x16x32 frag reads (no swizzle)
//  - reads spread 8/4/4/0 per phase; stages at p3/p4 only (post-read-drain);
//    counted vmcnt(6), vmcnt(0) at tail; T1 XCD swizzle; T5 setprio.
// ---------------------------------------------------------------------------

#define M_DIM 8192
#define N_DIM 4096
#define K_DIM 4096
#define BK    32
#define NT    (K_DIM / BK)   // 128 K-tiles

typedef __attribute__((ext_vector_type(8))) short bf16x8;
typedef __attribute__((ext_vector_type(4))) float f32x4;

#define PH_BAR() asm volatile("s_barrier" ::: "memory")
#define WAITV6() asm volatile("s_waitcnt vmcnt(6)" ::: "memory")
#define WAITV0() asm volatile("s_waitcnt vmcnt(0)" ::: "memory")

static __device__ __forceinline__ unsigned short f2bf(float f) {
    unsigned int u = __builtin_bit_cast(unsigned int, f);
    unsigned int r = (u + 0x7fffu + ((u >> 16) & 1u)) >> 16;
    return (unsigned short)r;
}

// --- conv_x: bf16(x) --------------------------------------------------------
__global__ __launch_bounds__(256) void conv_x_kernel(
    const float* __restrict__ x, unsigned short* __restrict__ xb) {
    size_t i = ((size_t)blockIdx.x * 256 + threadIdx.x) * 8;
    float4 a = *(const float4*)(x + i);
    float4 c = *(const float4*)(x + i + 4);
    union { unsigned short us[8]; uint4 v; } u;
    u.us[0] = f2bf(a.x); u.us[1] = f2bf(a.y); u.us[2] = f2bf(a.z); u.us[3] = f2bf(a.w);
    u.us[4] = f2bf(c.x); u.us[5] = f2bf(c.y); u.us[6] = f2bf(c.z); u.us[7] = f2bf(c.w);
    *(uint4*)(xb + i) = u.v;
}

// --- conv_w: bf16(W + B@A). 4 rows/block, lA read once per block. ----------
__global__ __launch_bounds__(512) void conv_w_kernel(
    const float* __restrict__ W, const float* __restrict__ lA,
    const float* __restrict__ lB, unsigned short* __restrict__ Wb) {
    const int nb = blockIdx.x * 4;        // 1024 blocks
    const int k0 = threadIdx.x * 8;       // 512 thr * 8 = 4096

    float acc[4][8];
#pragma unroll
    for (int r = 0; r < 4; ++r) {
        const float4* w4 = (const float4*)(W + (size_t)(nb + r) * K_DIM + k0);
        float4 v0 = w4[0], v1 = w4[1];
        acc[r][0] = v0.x; acc[r][1] = v0.y; acc[r][2] = v0.z; acc[r][3] = v0.w;
        acc[r][4] = v1.x; acc[r][5] = v1.y; acc[r][6] = v1.z; acc[r][7] = v1.w;
    }
    float brs[4][16];
#pragma unroll
    for (int r = 0; r < 4; ++r)
#pragma unroll
        for (int t = 0; t < 16; ++t) brs[r][t] = lB[(size_t)(nb + r) * 16 + t];

#pragma unroll
    for (int t = 0; t < 16; ++t) {
        const float4* a4 = (const float4*)(lA + (size_t)t * K_DIM + k0);
        float4 v0 = a4[0], v1 = a4[1];
        float av[8] = {v0.x, v0.y, v0.z, v0.w, v1.x, v1.y, v1.z, v1.w};
#pragma unroll
        for (int r = 0; r < 4; ++r)
#pragma unroll
            for (int j = 0; j < 8; ++j) acc[r][j] += brs[r][t] * av[j];
    }
#pragma unroll
    for (int r = 0; r < 4; ++r) {
        union { unsigned short us[8]; uint4 v; } u;
#pragma unroll
        for (int j = 0; j < 8; ++j) u.us[j] = f2bf(acc[r][j]);
        *(uint4*)(Wb + (size_t)(nb + r) * K_DIM + k0) = u.v;
    }
}

// --- gemm: 512x256 tile, BK=32, 8 waves, 4-phase counted-vmcnt schedule -----
__global__ __launch_bounds__(512, 2) void gemm_kernel(
    const unsigned short* __restrict__ A,   // [8192][4096] bf16
    const unsigned short* __restrict__ B,   // [4096][4096] bf16 (W')
    const float* __restrict__ bvec, const float* __restrict__ lbvec,
    float* __restrict__ C) {                // [8192][4096] f32
    const int tid = threadIdx.x;
    const int lane = tid & 63;
    const int wid = tid >> 6;        // 0..7
    const int wr = wid >> 1;         // 0..3  M-quarter (128 rows)
    const int wc = wid & 1;          // 0..1  N-half (128 cols)

    // T1: bijective XCD swizzle (256 % 8 == 0)
    const int bid = blockIdx.x;
    const int wg = (bid & 7) * 32 + (bid >> 3);
    const int mtile = wg >> 4;       // 0..15
    const int ntile = wg & 15;       // 0..15
    const int m0 = mtile * 512, n0 = ntile * 256;

    __shared__ __align__(16) unsigned short ldsA[2 * 512 * BK];  // 64 KiB
    __shared__ __align__(16) unsigned short ldsB[2 * 256 * BK];  // 32 KiB

    // --- staging: linear dest (no swizzle needed at 64-B rows) ---
    const int srow = lane >> 2;            // 0..15
    const int scol = (lane & 3) * 8;       // element col 0..24
    const unsigned short* aS = A + (size_t)(m0 + srow) * K_DIM + scol;
    const unsigned short* bS = B + (size_t)(n0 + srow) * K_DIM + scol;

    auto stageA = [&](int par_, int kt) {   // 4 chunks/wave, 32 total (512 rows)
#pragma unroll
        for (int s = 0; s < 4; ++s) {
            const int c = wid * 4 + s;
            const unsigned short* g = aS + (size_t)(c * 16) * K_DIM + kt * BK;
            __builtin_amdgcn_global_load_lds(
                (const __attribute__((address_space(1))) void*)g,
                (__attribute__((address_space(3))) void*)(ldsA + par_ * 16384 + c * 512),
                16, 0, 0);
        }
    };
    auto stageB = [&](int par_, int kt) {   // 2 chunks/wave, 16 total (256 rows)
#pragma unroll
        for (int s = 0; s < 2; ++s) {
            const int c = wid * 2 + s;
            const unsigned short* g = bS + (size_t)(c * 16) * K_DIM + kt * BK;
            __builtin_amdgcn_global_load_lds(
                (const __attribute__((address_space(1))) void*)g,
                (__attribute__((address_space(3))) void*)(ldsB + par_ * 8192 + c * 512),
                16, 0, 0);
        }
    };

    // --- read side: row*64B + (lane>>4)*16B; conflict-free, no swizzle ---
    const int rbyteA = (wr * 128 + (lane & 15)) * 64 + (lane >> 4) * 16;
    const int rbyteB = (wc * 128 + (lane & 15)) * 64 + (lane >> 4) * 16;

    auto readA = [&](int par_, int mf) -> bf16x8 {
        return *(const bf16x8*)((const char*)(ldsA + par_ * 16384) + mf * 1024 + rbyteA);
    };
    auto readB = [&](int par_, int nf) -> bf16x8 {
        return *(const bf16x8*)((const char*)(ldsB + par_ * 8192) + nf * 1024 + rbyteB);
    };

    f32x4 acc[8][8] = {};
    bf16x8 a[4], b[8];

    // --- prologue: t0 + t1 staged (6 loads each); drain t0 ---
    stageB(0, 0); stageA(0, 0);
    stageB(1, 1); stageA(1, 1);
    WAITV6();
    PH_BAR();

#define KTILE(kt, par)                                                          \
    {                                                                           \
        /* p1: read a0-3,b0-3 [8]; MFMA q(0,0) */                               \
        _Pragma("unroll") for (int i = 0; i < 4; ++i) a[i] = readA(par, i);     \
        _Pragma("unroll") for (int j = 0; j < 4; ++j) b[j] = readB(par, j);     \
        PH_BAR();                                                               \
        __builtin_amdgcn_s_setprio(1);                                          \
        _Pragma("unroll") for (int i = 0; i < 4; ++i)                           \
            _Pragma("unroll") for (int j = 0; j < 4; ++j)                       \
                acc[i][j] = __builtin_amdgcn_mfma_f32_16x16x32_bf16(            \
                    a[i], b[j], acc[i][j], 0, 0, 0);                            \
        __builtin_amdgcn_s_setprio(0);                                          \
        PH_BAR();                                                               \
        /* p2: read b4-7 [4]; MFMA q(0,1) */                                    \
        _Pragma("unroll") for (int j = 0; j < 4; ++j) b[4 + j] = readB(par, 4 + j); \
        PH_BAR();                                                               \
        __builtin_amdgcn_s_setprio(1);                                          \
        _Pragma("unroll") for (int i = 0; i < 4; ++i)                           \
            _Pragma("unroll") for (int j = 0; j < 4; ++j)                       \
                acc[i][4 + j] = __builtin_amdgcn_mfma_f32_16x16x32_bf16(        \
                    a[i], b[4 + j], acc[i][4 + j], 0, 0, 0);                    \
        __builtin_amdgcn_s_setprio(0);                                          \
        PH_BAR();                                                               \
        /* p3: read a4-7 [4] (reuse regs); stage B(t+2); MFMA q(1,0) */         \
        _Pragma("unroll") for (int i = 0; i < 4; ++i) a[i] = readA(par, 4 + i); \
        if ((kt) + 2 < NT) stageB(par, (kt) + 2);                               \
        PH_BAR();                                                               \
        __builtin_amdgcn_s_setprio(1);                                          \
        _Pragma("unroll") for (int i = 0; i < 4; ++i)                           \
            _Pragma("unroll") for (int j = 0; j < 4; ++j)                       \
                acc[4 + i][j] = __builtin_amdgcn_mfma_f32_16x16x32_bf16(        \
                    a[i], b[j], acc[4 + i][j], 0, 0, 0);                        \
        __builtin_amdgcn_s_setprio(0);                                          \
        PH_BAR();                                                               \
        /* p4: stage A(t+2); counted vmcnt; MFMA q(1,1) */                      \
        if ((kt) + 2 < NT) { stageA(par, (kt) + 2); WAITV6(); }                 \
        else { WAITV0(); }                                                      \
        PH_BAR();                                                               \
        __builtin_amdgcn_s_setprio(1);                                          \
        _Pragma("unroll") for (int i = 0; i < 4; ++i)                           \
            _Pragma("unroll") for (int j = 0; j < 4; ++j)                       \
                acc[4 + i][4 + j] = __builtin_amdgcn_mfma_f32_16x16x32_bf16(    \
                    a[i], b[4 + j], acc[4 + i][4 + j], 0, 0, 0);                \
        __builtin_amdgcn_s_setprio(0);                                          \
        PH_BAR();                                                               \
    }

#pragma unroll 1
    for (int kt = 0; kt < NT; kt += 2) {
        KTILE(kt, 0);
        KTILE(kt + 1, 1);
    }
#undef KTILE

    // --- epilogue: C = acc + (b + lora_bias); C/D layout col=lane&15,
    //     row=(lane>>4)*4+j (HW-verified) ---
#pragma unroll
    for (int nf = 0; nf < 8; ++nf) {
        const int gc = n0 + wc * 128 + nf * 16 + (lane & 15);
        const float bv = bvec[gc] + lbvec[gc];
#pragma unroll
        for (int mf = 0; mf < 8; ++mf) {
            const int gr0 = m0 + wr * 128 + mf * 16 + (lane >> 4) * 4;
            f32x4 v = acc[mf][nf];
#pragma unroll
            for (int j = 0; j < 4; ++j)
                C[(size_t)(gr0 + j) * N_DIM + gc] = v[j] + bv;
        }
    }
}

// --- Fallback: naive fp32 (only if ws too small) ----------------------------
__global__ __launch_bounds__(256) void naive_kernel(
    const float* __restrict__ x, const float* __restrict__ W,
    const float* __restrict__ b, const float* __restrict__ lA,
    const float* __restrict__ lB, const float* __restrict__ lb,
    float* __restrict__ out) {
    __shared__ float xs[K_DIM];
    __shared__ float ts[16];
    const int m = blockIdx.x;
    const int tid = threadIdx.x;
    for (int k = tid; k < K_DIM; k += 256) xs[k] = x[(size_t)m * K_DIM + k];
    if (tid < 16) ts[tid] = 0.f;
    __syncthreads();
    float part[16] = {};
    for (int k = tid * 16; k < tid * 16 + 16; ++k) {
        float xv = xs[k];
#pragma unroll
        for (int r = 0; r < 16; ++r) part[r] += xv * lA[(size_t)r * K_DIM + k];
    }
#pragma unroll
    for (int r = 0; r < 16; ++r) atomicAdd(&ts[r], part[r]);
    __syncthreads();
    const int n = blockIdx.y * 256 + tid;
    float acc = b[n] + lb[n];
#pragma unroll
    for (int r = 0; r < 16; ++r) acc += ts[r] * lB[(size_t)n * 16 + r];
    const float* wrow = W + (size_t)n * K_DIM;
    for (int k = 0; k < K_DIM; ++k) acc += xs[k] * wrow[k];
    out[(size_t)m * N_DIM + n] = acc;
}

// ---------------------------------------------------------------------------
extern "C" void kernel_launch(void* const* d_in, const int* in_sizes, int n_in,
                              void* d_out, int out_size, void* d_ws, size_t ws_size,
                              hipStream_t stream) {
    const float* x  = (const float*)d_in[0];
    const float* W  = (const float*)d_in[1];
    const float* b  = (const float*)d_in[2];
    const float* lA = (const float*)d_in[3];
    const float* lB = (const float*)d_in[4];
    const float* lb = (const float*)d_in[5];
    float* out = (float*)d_out;

    const size_t xb_bytes = (size_t)M_DIM * K_DIM * 2;  // 64 MiB
    const size_t wb_bytes = (size_t)N_DIM * K_DIM * 2;  // 32 MiB

    if (ws_size >= xb_bytes + wb_bytes) {
        unsigned short* xb = (unsigned short*)d_ws;
        unsigned short* wb = (unsigned short*)((char*)d_ws + xb_bytes);

        conv_x_kernel<<<(M_DIM * K_DIM) / (256 * 8), 256, 0, stream>>>(x, xb);
        conv_w_kernel<<<N_DIM / 4, 512, 0, stream>>>(W, lA, lB, wb);

        gemm_kernel<<<(M_DIM / 512) * (N_DIM / 256), 512, 0, stream>>>(xb, wb, b, lb, out);
    } else {
        dim3 grid(M_DIM, N_DIM / 256);
        naive_kernel<<<grid, 256, 0, stream>>>(x, W, b, lA, lB, lb, out);
    }
}

// Round 6
// 348.289 us; speedup vs baseline: 5.2545x; 5.2545x over previous
//
#include <hip/hip_runtime.h>
#include <hip/hip_bf16.h>
#include <stdint.h>

// ---------------------------------------------------------------------------
// LoRALinear: y = x @ (W + B@A)^T + (b + lora_bias)
// M=8192, N=4096, K=4096.
// R6: R3 geometry (256x256, BK=64, 8 waves 2Mx4N, acc[8][4]) +
//  - builtin s_barrier
//  - drain moved to p3 (vmcnt(4)) so t+1 is PUBLISHED (drain+barrier) before
//    the p4 pre-read of b0-1(t+1)  [R5 raced: pre-read before publication]
//  - balanced reads 8/4/8/4; stages at p3 (B) / p4 (A); T1/T2/T5.
// R4 lesson: per-wave acc must stay <=128 regs (acc[8][8] spilled).
// R5 lesson: vmcnt proves only THIS wave's loads; cross-wave visibility
//            requires drain-then-barrier before any read of others' chunks.
// ---------------------------------------------------------------------------

#define M_DIM 8192
#define N_DIM 4096
#define K_DIM 4096
#define NT    (K_DIM / 64)   // 64 K-tiles

typedef __attribute__((ext_vector_type(8))) short bf16x8;
typedef __attribute__((ext_vector_type(4))) float f32x4;

#define BARRIER() __builtin_amdgcn_s_barrier()
#define WAITV8() asm volatile("s_waitcnt vmcnt(8)" ::: "memory")
#define WAITV4() asm volatile("s_waitcnt vmcnt(4)" ::: "memory")
#define WAITV0() asm volatile("s_waitcnt vmcnt(0)" ::: "memory")

static __device__ __forceinline__ unsigned short f2bf(float f) {
    unsigned int u = __builtin_bit_cast(unsigned int, f);
    unsigned int r = (u + 0x7fffu + ((u >> 16) & 1u)) >> 16;
    return (unsigned short)r;
}

// --- conv_x: bf16(x) --------------------------------------------------------
__global__ __launch_bounds__(256) void conv_x_kernel(
    const float* __restrict__ x, unsigned short* __restrict__ xb) {
    size_t i = ((size_t)blockIdx.x * 256 + threadIdx.x) * 8;
    float4 a = *(const float4*)(x + i);
    float4 c = *(const float4*)(x + i + 4);
    union { unsigned short us[8]; uint4 v; } u;
    u.us[0] = f2bf(a.x); u.us[1] = f2bf(a.y); u.us[2] = f2bf(a.z); u.us[3] = f2bf(a.w);
    u.us[4] = f2bf(c.x); u.us[5] = f2bf(c.y); u.us[6] = f2bf(c.z); u.us[7] = f2bf(c.w);
    *(uint4*)(xb + i) = u.v;
}

// --- conv_w: bf16(W + B@A). 4 rows/block, lA read once per block. ----------
__global__ __launch_bounds__(512) void conv_w_kernel(
    const float* __restrict__ W, const float* __restrict__ lA,
    const float* __restrict__ lB, unsigned short* __restrict__ Wb) {
    const int nb = blockIdx.x * 4;        // 1024 blocks
    const int k0 = threadIdx.x * 8;       // 512 thr * 8 = 4096

    float acc[4][8];
#pragma unroll
    for (int r = 0; r < 4; ++r) {
        const float4* w4 = (const float4*)(W + (size_t)(nb + r) * K_DIM + k0);
        float4 v0 = w4[0], v1 = w4[1];
        acc[r][0] = v0.x; acc[r][1] = v0.y; acc[r][2] = v0.z; acc[r][3] = v0.w;
        acc[r][4] = v1.x; acc[r][5] = v1.y; acc[r][6] = v1.z; acc[r][7] = v1.w;
    }
    float brs[4][16];
#pragma unroll
    for (int r = 0; r < 4; ++r)
#pragma unroll
        for (int t = 0; t < 16; ++t) brs[r][t] = lB[(size_t)(nb + r) * 16 + t];

#pragma unroll
    for (int t = 0; t < 16; ++t) {
        const float4* a4 = (const float4*)(lA + (size_t)t * K_DIM + k0);
        float4 v0 = a4[0], v1 = a4[1];
        float av[8] = {v0.x, v0.y, v0.z, v0.w, v1.x, v1.y, v1.z, v1.w};
#pragma unroll
        for (int r = 0; r < 4; ++r)
#pragma unroll
            for (int j = 0; j < 8; ++j) acc[r][j] += brs[r][t] * av[j];
    }
#pragma unroll
    for (int r = 0; r < 4; ++r) {
        union { unsigned short us[8]; uint4 v; } u;
#pragma unroll
        for (int j = 0; j < 8; ++j) u.us[j] = f2bf(acc[r][j]);
        *(uint4*)(Wb + (size_t)(nb + r) * K_DIM + k0) = u.v;
    }
}

// --- gemm: 256x256 tile, BK=64, 8 waves, 4-phase counted-vmcnt schedule -----
__global__ __launch_bounds__(512, 2) void gemm_kernel(
    const unsigned short* __restrict__ A,   // [8192][4096] bf16
    const unsigned short* __restrict__ B,   // [4096][4096] bf16 (W')
    const float* __restrict__ bvec, const float* __restrict__ lbvec,
    float* __restrict__ C) {
    const int tid = threadIdx.x;
    const int lane = tid & 63;
    const int wid = tid >> 6;        // 0..7
    const int wr = wid >> 2;         // 0..1  M-half (128 rows)
    const int wc = wid & 3;          // 0..3  N-quarter (64 cols)

    // T1: bijective XCD swizzle (512 % 8 == 0)
    const int bid = blockIdx.x;
    const int wg = (bid & 7) * 64 + (bid >> 3);
    const int mtile = wg >> 4;       // 0..31
    const int ntile = wg & 15;       // 0..15
    const int m0 = mtile * 256, n0 = ntile * 256;

    __shared__ __align__(16) unsigned short ldsA[2 * 2 * 128 * 64];  // 64 KiB
    __shared__ __align__(16) unsigned short ldsB[2 * 2 * 128 * 64];  // 64 KiB

    // --- staging (write side): linear LDS dest, inverse-swizzled global src
    const int lr8 = lane >> 3;             // 0..7
    const int cch = (lane & 7) ^ lr8;      // swizzled 16B-chunk index
    const unsigned short* aSb = A + (size_t)(m0 + lr8) * K_DIM + cch * 8;
    const unsigned short* bSb = B + (size_t)(n0 + lr8) * K_DIM + cch * 8;

    auto stageA = [&](int par_, int h, int kt) {
#pragma unroll
        for (int s = 0; s < 2; ++s) {
            const int j = wid * 2 + s;
            const unsigned short* g = aSb + (size_t)(h * 128 + j * 8) * K_DIM + kt * 64;
            __builtin_amdgcn_global_load_lds(
                (const __attribute__((address_space(1))) void*)g,
                (__attribute__((address_space(3))) void*)(ldsA + (par_ * 2 + h) * 8192 + j * 512),
                16, 0, 0);
        }
    };
    auto stageB = [&](int par_, int h, int kt) {
#pragma unroll
        for (int s = 0; s < 2; ++s) {
            const int j = wid * 2 + s;
            const unsigned short* g = bSb + (size_t)(h * 128 + j * 8) * K_DIM + kt * 64;
            __builtin_amdgcn_global_load_lds(
                (const __attribute__((address_space(1))) void*)g,
                (__attribute__((address_space(3))) void*)(ldsB + (par_ * 2 + h) * 8192 + j * 512),
                16, 0, 0);
        }
    };

    // --- read side (T2 swizzle on the byte address) ---
    const int rowByte = (lane & 15) * 128;
    const int swz = (lane & 7) << 4;
    const int kc0 = (0 * 64 + (lane >> 4) * 16) ^ swz;
    const int kc1 = (1 * 64 + (lane >> 4) * 16) ^ swz;
    const int baseBoff = (wc & 1) * 4096;  // 64-row sub-block within 128-row half

    auto readA = [&](int par_, int mf, int kk) -> bf16x8 {
        const char* p = (const char*)(ldsA + (par_ * 2 + wr) * 8192 + mf * 1024) +
                        rowByte + (kk ? kc1 : kc0);
        return *(const bf16x8*)p;
    };
    auto readB = [&](int par_, int nf, int kk) -> bf16x8 {
        const char* p = (const char*)(ldsB + (par_ * 2 + (wc >> 1)) * 8192 + baseBoff + nf * 1024) +
                        rowByte + (kk ? kc1 : kc0);
        return *(const bf16x8*)p;
    };

    f32x4 acc[8][4] = {};
    bf16x8 a[4][2], b[4][2];

    auto mfmaQ = [&](int qm, int qn) {   // 16 MFMA: 4 mf x 2 nf x 2 kk
#pragma unroll
        for (int i = 0; i < 4; ++i)
#pragma unroll
            for (int jn = 0; jn < 2; ++jn)
#pragma unroll
                for (int kk = 0; kk < 2; ++kk)
                    acc[qm * 4 + i][qn * 2 + jn] = __builtin_amdgcn_mfma_f32_16x16x32_bf16(
                        a[i][kk], b[qn * 2 + jn][kk], acc[qm * 4 + i][qn * 2 + jn], 0, 0, 0);
    };

    // --- prologue: stage t0,t1 (16 loads); drain t0; PUBLISH (barrier);
    //     then pre-read b0-1(t0) ---
    stageB(0, 0, 0); stageB(0, 1, 0); stageA(0, 0, 0); stageA(0, 1, 0);
    stageB(1, 0, 1); stageB(1, 1, 1); stageA(1, 0, 1); stageA(1, 1, 1);
    WAITV8();
    BARRIER();
#pragma unroll
    for (int nf = 0; nf < 2; ++nf)
#pragma unroll
        for (int kk = 0; kk < 2; ++kk) b[nf][kk] = readB(0, nf, kk);

    // Per K-tile: p1=8(a0-3) p2=4(b2-3) p3=8(a4-7)+stageB+drain(t+1) p4=stageA+4(b0-1 t+1)
#define KTILE(kt, par)                                                          \
    {                                                                           \
        /* p1: read a0-3; MFMA Q(0,0) (b0-1 already in regs) */                 \
        _Pragma("unroll") for (int i = 0; i < 4; ++i)                           \
            _Pragma("unroll") for (int kk = 0; kk < 2; ++kk)                    \
                a[i][kk] = readA(par, i, kk);                                    \
        BARRIER();                                                              \
        __builtin_amdgcn_s_setprio(1); mfmaQ(0, 0); __builtin_amdgcn_s_setprio(0); \
        BARRIER();                                                              \
        /* p2: read b2-3; MFMA Q(0,1) */                                        \
        _Pragma("unroll") for (int nf = 2; nf < 4; ++nf)                        \
            _Pragma("unroll") for (int kk = 0; kk < 2; ++kk)                    \
                b[nf][kk] = readB(par, nf, kk);                                  \
        BARRIER();                                                              \
        __builtin_amdgcn_s_setprio(1); mfmaQ(0, 1); __builtin_amdgcn_s_setprio(0); \
        BARRIER();                                                              \
        /* p3: read a4-7; stage B(t+2); drain t+1 (vmcnt4 / 0 at tail);         \
           closing barrier PUBLISHES t+1 */                                     \
        _Pragma("unroll") for (int i = 0; i < 4; ++i)                           \
            _Pragma("unroll") for (int kk = 0; kk < 2; ++kk)                    \
                a[i][kk] = readA(par, 4 + i, kk);                                \
        if ((kt) + 2 < NT) { stageB(par, 0, (kt) + 2); stageB(par, 1, (kt) + 2); WAITV4(); } \
        else { WAITV0(); }                                                      \
        BARRIER();                                                              \
        __builtin_amdgcn_s_setprio(1); mfmaQ(1, 0); __builtin_amdgcn_s_setprio(0); \
        BARRIER();                                                              \
        /* p4: stage A(t+2); pre-read b0-1(t+1) [published at p3]; MFMA Q(1,1) */ \
        if ((kt) + 2 < NT) { stageA(par, 0, (kt) + 2); stageA(par, 1, (kt) + 2); } \
        if ((kt) + 1 < NT) {                                                    \
            _Pragma("unroll") for (int nf = 0; nf < 2; ++nf)                    \
                _Pragma("unroll") for (int kk = 0; kk < 2; ++kk)                \
                    b[nf][kk] = readB((par) ^ 1, nf, kk);                        \
        }                                                                       \
        BARRIER();                                                              \
        __builtin_amdgcn_s_setprio(1); mfmaQ(1, 1); __builtin_amdgcn_s_setprio(0); \
        BARRIER();                                                              \
    }

#pragma unroll 1
    for (int kt = 0; kt < NT; kt += 2) {
        KTILE(kt, 0);
        KTILE(kt + 1, 1);
    }
#undef KTILE

    // --- epilogue: C = acc + (b + lora_bias); C/D layout col=lane&15,
    //     row=(lane>>4)*4+j (HW-verified) ---
#pragma unroll
    for (int nf = 0; nf < 4; ++nf) {
        const int gc = n0 + wc * 64 + nf * 16 + (lane & 15);
        const float bv = bvec[gc] + lbvec[gc];
#pragma unroll
        for (int mf = 0; mf < 8; ++mf) {
            const int gr0 = m0 + wr * 128 + mf * 16 + (lane >> 4) * 4;
            f32x4 v = acc[mf][nf];
#pragma unroll
            for (int j = 0; j < 4; ++j)
                C[(size_t)(gr0 + j) * N_DIM + gc] = v[j] + bv;
        }
    }
}

// --- Fallback: naive fp32 (only if ws too small) ----------------------------
__global__ __launch_bounds__(256) void naive_kernel(
    const float* __restrict__ x, const float* __restrict__ W,
    const float* __restrict__ b, const float* __restrict__ lA,
    const float* __restrict__ lB, const float* __restrict__ lb,
    float* __restrict__ out) {
    __shared__ float xs[K_DIM];
    __shared__ float ts[16];
    const int m = blockIdx.x;
    const int tid = threadIdx.x;
    for (int k = tid; k < K_DIM; k += 256) xs[k] = x[(size_t)m * K_DIM + k];
    if (tid < 16) ts[tid] = 0.f;
    __syncthreads();
    float part[16] = {};
    for (int k = tid * 16; k < tid * 16 + 16; ++k) {
        float xv = xs[k];
#pragma unroll
        for (int r = 0; r < 16; ++r) part[r] += xv * lA[(size_t)r * K_DIM + k];
    }
#pragma unroll
    for (int r = 0; r < 16; ++r) atomicAdd(&ts[r], part[r]);
    __syncthreads();
    const int n = blockIdx.y * 256 + tid;
    float acc = b[n] + lb[n];
#pragma unroll
    for (int r = 0; r < 16; ++r) acc += ts[r] * lB[(size_t)n * 16 + r];
    const float* wrow = W + (size_t)n * K_DIM;
    for (int k = 0; k < K_DIM; ++k) acc += xs[k] * wrow[k];
    out[(size_t)m * N_DIM + n] = acc;
}

// ---------------------------------------------------------------------------
extern "C" void kernel_launch(void* const* d_in, const int* in_sizes, int n_in,
                              void* d_out, int out_size, void* d_ws, size_t ws_size,
                              hipStream_t stream) {
    const float* x  = (const float*)d_in[0];
    const float* W  = (const float*)d_in[1];
    const float* b  = (const float*)d_in[2];
    const float* lA = (const float*)d_in[3];
    const float* lB = (const float*)d_in[4];
    const float* lb = (const float*)d_in[5];
    float* out = (float*)d_out;

    const size_t xb_bytes = (size_t)M_DIM * K_DIM * 2;  // 64 MiB
    const size_t wb_bytes = (size_t)N_DIM * K_DIM * 2;  // 32 MiB

    if (ws_size >= xb_bytes + wb_bytes) {
        unsigned short* xb = (unsigned short*)d_ws;
        unsigned short* wb = (unsigned short*)((char*)d_ws + xb_bytes);

        conv_x_kernel<<<(M_DIM * K_DIM) / (256 * 8), 256, 0, stream>>>(x, xb);
        conv_w_kernel<<<N_DIM / 4, 512, 0, stream>>>(W, lA, lB, wb);

        gemm_kernel<<<(M_DIM / 256) * (N_DIM / 256), 512, 0, stream>>>(xb, wb, b, lb, out);
    } else {
        dim3 grid(M_DIM, N_DIM / 256);
        naive_kernel<<<grid, 256, 0, stream>>>(x, W, b, lA, lB, lb, out);
    }
}

// Round 7
// 325.844 us; speedup vs baseline: 5.6165x; 1.0689x over previous
//
#include <hip/hip_runtime.h>
#include <hip/hip_bf16.h>
#include <stdint.h>

// ---------------------------------------------------------------------------
// LoRALinear: y = x @ (W + B@A)^T + (b + lora_bias)
// M=8192, N=4096, K=4096.
// R8: R6 schedule unchanged. ONE change: block->tile mapping is now
// XCD-column-resident: each XCD owns 2 ntile columns (B panels, 4MB -> fits
// its private L2) and walks mtiles; A panels stream with 2x concurrent reuse.
// Theory: R3/R6 ~300us were L3-bandwidth-bound on B-panel re-reads
// (32MB concurrent B working set per XCD vs 4MB L2).
// R4 lesson: per-wave acc must stay <=128 regs (acc[8][8] spilled).
// R5 lesson: vmcnt proves only THIS wave's loads; cross-wave visibility
//            requires drain-then-barrier before any read of others' chunks.
// ---------------------------------------------------------------------------

#define M_DIM 8192
#define N_DIM 4096
#define K_DIM 4096
#define NT    (K_DIM / 64)   // 64 K-tiles

typedef __attribute__((ext_vector_type(8))) short bf16x8;
typedef __attribute__((ext_vector_type(4))) float f32x4;

#define BARRIER() __builtin_amdgcn_s_barrier()
#define WAITV8() asm volatile("s_waitcnt vmcnt(8)" ::: "memory")
#define WAITV4() asm volatile("s_waitcnt vmcnt(4)" ::: "memory")
#define WAITV0() asm volatile("s_waitcnt vmcnt(0)" ::: "memory")

static __device__ __forceinline__ unsigned short f2bf(float f) {
    unsigned int u = __builtin_bit_cast(unsigned int, f);
    unsigned int r = (u + 0x7fffu + ((u >> 16) & 1u)) >> 16;
    return (unsigned short)r;
}

// --- conv_x: bf16(x) --------------------------------------------------------
__global__ __launch_bounds__(256) void conv_x_kernel(
    const float* __restrict__ x, unsigned short* __restrict__ xb) {
    size_t i = ((size_t)blockIdx.x * 256 + threadIdx.x) * 8;
    float4 a = *(const float4*)(x + i);
    float4 c = *(const float4*)(x + i + 4);
    union { unsigned short us[8]; uint4 v; } u;
    u.us[0] = f2bf(a.x); u.us[1] = f2bf(a.y); u.us[2] = f2bf(a.z); u.us[3] = f2bf(a.w);
    u.us[4] = f2bf(c.x); u.us[5] = f2bf(c.y); u.us[6] = f2bf(c.z); u.us[7] = f2bf(c.w);
    *(uint4*)(xb + i) = u.v;
}

// --- conv_w: bf16(W + B@A). 4 rows/block, lA read once per block. ----------
__global__ __launch_bounds__(512) void conv_w_kernel(
    const float* __restrict__ W, const float* __restrict__ lA,
    const float* __restrict__ lB, unsigned short* __restrict__ Wb) {
    const int nb = blockIdx.x * 4;        // 1024 blocks
    const int k0 = threadIdx.x * 8;       // 512 thr * 8 = 4096

    float acc[4][8];
#pragma unroll
    for (int r = 0; r < 4; ++r) {
        const float4* w4 = (const float4*)(W + (size_t)(nb + r) * K_DIM + k0);
        float4 v0 = w4[0], v1 = w4[1];
        acc[r][0] = v0.x; acc[r][1] = v0.y; acc[r][2] = v0.z; acc[r][3] = v0.w;
        acc[r][4] = v1.x; acc[r][5] = v1.y; acc[r][6] = v1.z; acc[r][7] = v1.w;
    }
    float brs[4][16];
#pragma unroll
    for (int r = 0; r < 4; ++r)
#pragma unroll
        for (int t = 0; t < 16; ++t) brs[r][t] = lB[(size_t)(nb + r) * 16 + t];

#pragma unroll
    for (int t = 0; t < 16; ++t) {
        const float4* a4 = (const float4*)(lA + (size_t)t * K_DIM + k0);
        float4 v0 = a4[0], v1 = a4[1];
        float av[8] = {v0.x, v0.y, v0.z, v0.w, v1.x, v1.y, v1.z, v1.w};
#pragma unroll
        for (int r = 0; r < 4; ++r)
#pragma unroll
            for (int j = 0; j < 8; ++j) acc[r][j] += brs[r][t] * av[j];
    }
#pragma unroll
    for (int r = 0; r < 4; ++r) {
        union { unsigned short us[8]; uint4 v; } u;
#pragma unroll
        for (int j = 0; j < 8; ++j) u.us[j] = f2bf(acc[r][j]);
        *(uint4*)(Wb + (size_t)(nb + r) * K_DIM + k0) = u.v;
    }
}

// --- gemm: 256x256 tile, BK=64, 8 waves, 4-phase counted-vmcnt schedule -----
__global__ __launch_bounds__(512, 2) void gemm_kernel(
    const unsigned short* __restrict__ A,   // [8192][4096] bf16
    const unsigned short* __restrict__ B,   // [4096][4096] bf16 (W')
    const float* __restrict__ bvec, const float* __restrict__ lbvec,
    float* __restrict__ C) {
    const int tid = threadIdx.x;
    const int lane = tid & 63;
    const int wid = tid >> 6;        // 0..7
    const int wr = wid >> 2;         // 0..1  M-half (128 rows)
    const int wc = wid & 3;          // 0..3  N-quarter (64 cols)

    // XCD-column-resident mapping: XCD = bid&7 owns ntiles {2x, 2x+1};
    // walks mtiles. Concurrent B working set per XCD = 4MB (L2-resident);
    // A panels stream with 2x concurrent ntile reuse.
    const int bid = blockIdx.x;
    const int ntile = (bid & 7) * 2 + ((bid >> 3) & 1);  // 0..15
    const int mtile = bid >> 4;                          // 0..31
    const int m0 = mtile * 256, n0 = ntile * 256;

    __shared__ __align__(16) unsigned short ldsA[2 * 2 * 128 * 64];  // 64 KiB
    __shared__ __align__(16) unsigned short ldsB[2 * 2 * 128 * 64];  // 64 KiB

    // --- staging (write side): linear LDS dest, inverse-swizzled global src
    const int lr8 = lane >> 3;             // 0..7
    const int cch = (lane & 7) ^ lr8;      // swizzled 16B-chunk index
    const unsigned short* aSb = A + (size_t)(m0 + lr8) * K_DIM + cch * 8;
    const unsigned short* bSb = B + (size_t)(n0 + lr8) * K_DIM + cch * 8;

    auto stageA = [&](int par_, int h, int kt) {
#pragma unroll
        for (int s = 0; s < 2; ++s) {
            const int j = wid * 2 + s;
            const unsigned short* g = aSb + (size_t)(h * 128 + j * 8) * K_DIM + kt * 64;
            __builtin_amdgcn_global_load_lds(
                (const __attribute__((address_space(1))) void*)g,
                (__attribute__((address_space(3))) void*)(ldsA + (par_ * 2 + h) * 8192 + j * 512),
                16, 0, 0);
        }
    };
    auto stageB = [&](int par_, int h, int kt) {
#pragma unroll
        for (int s = 0; s < 2; ++s) {
            const int j = wid * 2 + s;
            const unsigned short* g = bSb + (size_t)(h * 128 + j * 8) * K_DIM + kt * 64;
            __builtin_amdgcn_global_load_lds(
                (const __attribute__((address_space(1))) void*)g,
                (__attribute__((address_space(3))) void*)(ldsB + (par_ * 2 + h) * 8192 + j * 512),
                16, 0, 0);
        }
    };

    // --- read side (T2 swizzle on the byte address) ---
    const int rowByte = (lane & 15) * 128;
    const int swz = (lane & 7) << 4;
    const int kc0 = (0 * 64 + (lane >> 4) * 16) ^ swz;
    const int kc1 = (1 * 64 + (lane >> 4) * 16) ^ swz;
    const int baseBoff = (wc & 1) * 4096;  // 64-row sub-block within 128-row half

    auto readA = [&](int par_, int mf, int kk) -> bf16x8 {
        const char* p = (const char*)(ldsA + (par_ * 2 + wr) * 8192 + mf * 1024) +
                        rowByte + (kk ? kc1 : kc0);
        return *(const bf16x8*)p;
    };
    auto readB = [&](int par_, int nf, int kk) -> bf16x8 {
        const char* p = (const char*)(ldsB + (par_ * 2 + (wc >> 1)) * 8192 + baseBoff + nf * 1024) +
                        rowByte + (kk ? kc1 : kc0);
        return *(const bf16x8*)p;
    };

    f32x4 acc[8][4] = {};
    bf16x8 a[4][2], b[4][2];

    auto mfmaQ = [&](int qm, int qn) {   // 16 MFMA: 4 mf x 2 nf x 2 kk
#pragma unroll
        for (int i = 0; i < 4; ++i)
#pragma unroll
            for (int jn = 0; jn < 2; ++jn)
#pragma unroll
                for (int kk = 0; kk < 2; ++kk)
                    acc[qm * 4 + i][qn * 2 + jn] = __builtin_amdgcn_mfma_f32_16x16x32_bf16(
                        a[i][kk], b[qn * 2 + jn][kk], acc[qm * 4 + i][qn * 2 + jn], 0, 0, 0);
    };

    // --- prologue: stage t0,t1 (16 loads); drain t0; PUBLISH (barrier);
    //     then pre-read b0-1(t0) ---
    stageB(0, 0, 0); stageB(0, 1, 0); stageA(0, 0, 0); stageA(0, 1, 0);
    stageB(1, 0, 1); stageB(1, 1, 1); stageA(1, 0, 1); stageA(1, 1, 1);
    WAITV8();
    BARRIER();
#pragma unroll
    for (int nf = 0; nf < 2; ++nf)
#pragma unroll
        for (int kk = 0; kk < 2; ++kk) b[nf][kk] = readB(0, nf, kk);

    // Per K-tile: p1=8(a0-3) p2=4(b2-3) p3=8(a4-7)+stageB+drain(t+1) p4=stageA+4(b0-1 t+1)
#define KTILE(kt, par)                                                          \
    {                                                                           \
        /* p1: read a0-3; MFMA Q(0,0) (b0-1 already in regs) */                 \
        _Pragma("unroll") for (int i = 0; i < 4; ++i)                           \
            _Pragma("unroll") for (int kk = 0; kk < 2; ++kk)                    \
                a[i][kk] = readA(par, i, kk);                                    \
        BARRIER();                                                              \
        __builtin_amdgcn_s_setprio(1); mfmaQ(0, 0); __builtin_amdgcn_s_setprio(0); \
        BARRIER();                                                              \
        /* p2: read b2-3; MFMA Q(0,1) */                                        \
        _Pragma("unroll") for (int nf = 2; nf < 4; ++nf)                        \
            _Pragma("unroll") for (int kk = 0; kk < 2; ++kk)                    \
                b[nf][kk] = readB(par, nf, kk);                                  \
        BARRIER();                                                              \
        __builtin_amdgcn_s_setprio(1); mfmaQ(0, 1); __builtin_amdgcn_s_setprio(0); \
        BARRIER();                                                              \
        /* p3: read a4-7; stage B(t+2); drain t+1 (vmcnt4 / 0 at tail);         \
           closing barrier PUBLISHES t+1 */                                     \
        _Pragma("unroll") for (int i = 0; i < 4; ++i)                           \
            _Pragma("unroll") for (int kk = 0; kk < 2; ++kk)                    \
                a[i][kk] = readA(par, 4 + i, kk);                                \
        if ((kt) + 2 < NT) { stageB(par, 0, (kt) + 2); stageB(par, 1, (kt) + 2); WAITV4(); } \
        else { WAITV0(); }                                                      \
        BARRIER();                                                              \
        __builtin_amdgcn_s_setprio(1); mfmaQ(1, 0); __builtin_amdgcn_s_setprio(0); \
        BARRIER();                                                              \
        /* p4: stage A(t+2); pre-read b0-1(t+1) [published at p3]; MFMA Q(1,1) */ \
        if ((kt) + 2 < NT) { stageA(par, 0, (kt) + 2); stageA(par, 1, (kt) + 2); } \
        if ((kt) + 1 < NT) {                                                    \
            _Pragma("unroll") for (int nf = 0; nf < 2; ++nf)                    \
                _Pragma("unroll") for (int kk = 0; kk < 2; ++kk)                \
                    b[nf][kk] = readB((par) ^ 1, nf, kk);                        \
        }                                                                       \
        BARRIER();                                                              \
        __builtin_amdgcn_s_setprio(1); mfmaQ(1, 1); __builtin_amdgcn_s_setprio(0); \
        BARRIER();                                                              \
    }

#pragma unroll 1
    for (int kt = 0; kt < NT; kt += 2) {
        KTILE(kt, 0);
        KTILE(kt + 1, 1);
    }
#undef KTILE

    // --- epilogue: C = acc + (b + lora_bias); C/D layout col=lane&15,
    //     row=(lane>>4)*4+j (HW-verified) ---
#pragma unroll
    for (int nf = 0; nf < 4; ++nf) {
        const int gc = n0 + wc * 64 + nf * 16 + (lane & 15);
        const float bv = bvec[gc] + lbvec[gc];
#pragma unroll
        for (int mf = 0; mf < 8; ++mf) {
            const int gr0 = m0 + wr * 128 + mf * 16 + (lane >> 4) * 4;
            f32x4 v = acc[mf][nf];
#pragma unroll
            for (int j = 0; j < 4; ++j)
                C[(size_t)(gr0 + j) * N_DIM + gc] = v[j] + bv;
        }
    }
}

// --- Fallback: naive fp32 (only if ws too small) ----------------------------
__global__ __launch_bounds__(256) void naive_kernel(
    const float* __restrict__ x, const float* __restrict__ W,
    const float* __restrict__ b, const float* __restrict__ lA,
    const float* __restrict__ lB, const float* __restrict__ lb,
    float* __restrict__ out) {
    __shared__ float xs[K_DIM];
    __shared__ float ts[16];
    const int m = blockIdx.x;
    const int tid = threadIdx.x;
    for (int k = tid; k < K_DIM; k += 256) xs[k] = x[(size_t)m * K_DIM + k];
    if (tid < 16) ts[tid] = 0.f;
    __syncthreads();
    float part[16] = {};
    for (int k = tid * 16; k < tid * 16 + 16; ++k) {
        float xv = xs[k];
#pragma unroll
        for (int r = 0; r < 16; ++r) part[r] += xv * lA[(size_t)r * K_DIM + k];
    }
#pragma unroll
    for (int r = 0; r < 16; ++r) atomicAdd(&ts[r], part[r]);
    __syncthreads();
    const int n = blockIdx.y * 256 + tid;
    float acc = b[n] + lb[n];
#pragma unroll
    for (int r = 0; r < 16; ++r) acc += ts[r] * lB[(size_t)n * 16 + r];
    const float* wrow = W + (size_t)n * K_DIM;
    for (int k = 0; k < K_DIM; ++k) acc += xs[k] * wrow[k];
    out[(size_t)m * N_DIM + n] = acc;
}

// ---------------------------------------------------------------------------
extern "C" void kernel_launch(void* const* d_in, const int* in_sizes, int n_in,
                              void* d_out, int out_size, void* d_ws, size_t ws_size,
                              hipStream_t stream) {
    const float* x  = (const float*)d_in[0];
    const float* W  = (const float*)d_in[1];
    const float* b  = (const float*)d_in[2];
    const float* lA = (const float*)d_in[3];
    const float* lB = (const float*)d_in[4];
    const float* lb = (const float*)d_in[5];
    float* out = (float*)d_out;

    const size_t xb_bytes = (size_t)M_DIM * K_DIM * 2;  // 64 MiB
    const size_t wb_bytes = (size_t)N_DIM * K_DIM * 2;  // 32 MiB

    if (ws_size >= xb_bytes + wb_bytes) {
        unsigned short* xb = (unsigned short*)d_ws;
        unsigned short* wb = (unsigned short*)((char*)d_ws + xb_bytes);

        conv_x_kernel<<<(M_DIM * K_DIM) / (256 * 8), 256, 0, stream>>>(x, xb);
        conv_w_kernel<<<N_DIM / 4, 512, 0, stream>>>(W, lA, lB, wb);

        gemm_kernel<<<(M_DIM / 256) * (N_DIM / 256), 512, 0, stream>>>(xb, wb, b, lb, out);
    } else {
        dim3 grid(M_DIM, N_DIM / 256);
        naive_kernel<<<grid, 256, 0, stream>>>(x, W, b, lA, lB, lb, out);
    }
}

// Round 8
// 322.264 us; speedup vs baseline: 5.6789x; 1.0111x over previous
//
#include <hip/hip_runtime.h>
#include <hip/hip_bf16.h>
#include <stdint.h>

// ---------------------------------------------------------------------------
// LoRALinear: y = x @ (W + B@A)^T + (b + lora_bias)
// M=8192, N=4096, K=4096.
// R8: identical to R7 except the C epilogue uses NON-TEMPORAL stores.
// Theory: R7 is staging-rate-bound (2GB staged @ 6.8 TB/s, 2.28us/K-tile >
// compute 1.8us); FETCH=297MB (3x ideal) says panels get evicted from L2/L3
// by the 137MB streaming C writeback. NT stores keep C out of the caches.
// R4 lesson: per-wave acc must stay <=128 regs (acc[8][8] spilled).
// R5 lesson: vmcnt proves only THIS wave's loads; cross-wave visibility
//            requires drain-then-barrier before any read of others' chunks.
// R7 lesson: MfmaUtil 40.7 / conflicts 0 / schedule fine; binder is staging.
// ---------------------------------------------------------------------------

#define M_DIM 8192
#define N_DIM 4096
#define K_DIM 4096
#define NT    (K_DIM / 64)   // 64 K-tiles

typedef __attribute__((ext_vector_type(8))) short bf16x8;
typedef __attribute__((ext_vector_type(4))) float f32x4;

#define BARRIER() __builtin_amdgcn_s_barrier()
#define WAITV8() asm volatile("s_waitcnt vmcnt(8)" ::: "memory")
#define WAITV4() asm volatile("s_waitcnt vmcnt(4)" ::: "memory")
#define WAITV0() asm volatile("s_waitcnt vmcnt(0)" ::: "memory")

static __device__ __forceinline__ unsigned short f2bf(float f) {
    unsigned int u = __builtin_bit_cast(unsigned int, f);
    unsigned int r = (u + 0x7fffu + ((u >> 16) & 1u)) >> 16;
    return (unsigned short)r;
}

// --- conv_x: bf16(x) --------------------------------------------------------
__global__ __launch_bounds__(256) void conv_x_kernel(
    const float* __restrict__ x, unsigned short* __restrict__ xb) {
    size_t i = ((size_t)blockIdx.x * 256 + threadIdx.x) * 8;
    float4 a = *(const float4*)(x + i);
    float4 c = *(const float4*)(x + i + 4);
    union { unsigned short us[8]; uint4 v; } u;
    u.us[0] = f2bf(a.x); u.us[1] = f2bf(a.y); u.us[2] = f2bf(a.z); u.us[3] = f2bf(a.w);
    u.us[4] = f2bf(c.x); u.us[5] = f2bf(c.y); u.us[6] = f2bf(c.z); u.us[7] = f2bf(c.w);
    *(uint4*)(xb + i) = u.v;
}

// --- conv_w: bf16(W + B@A). 4 rows/block, lA read once per block. ----------
__global__ __launch_bounds__(512) void conv_w_kernel(
    const float* __restrict__ W, const float* __restrict__ lA,
    const float* __restrict__ lB, unsigned short* __restrict__ Wb) {
    const int nb = blockIdx.x * 4;        // 1024 blocks
    const int k0 = threadIdx.x * 8;       // 512 thr * 8 = 4096

    float acc[4][8];
#pragma unroll
    for (int r = 0; r < 4; ++r) {
        const float4* w4 = (const float4*)(W + (size_t)(nb + r) * K_DIM + k0);
        float4 v0 = w4[0], v1 = w4[1];
        acc[r][0] = v0.x; acc[r][1] = v0.y; acc[r][2] = v0.z; acc[r][3] = v0.w;
        acc[r][4] = v1.x; acc[r][5] = v1.y; acc[r][6] = v1.z; acc[r][7] = v1.w;
    }
    float brs[4][16];
#pragma unroll
    for (int r = 0; r < 4; ++r)
#pragma unroll
        for (int t = 0; t < 16; ++t) brs[r][t] = lB[(size_t)(nb + r) * 16 + t];

#pragma unroll
    for (int t = 0; t < 16; ++t) {
        const float4* a4 = (const float4*)(lA + (size_t)t * K_DIM + k0);
        float4 v0 = a4[0], v1 = a4[1];
        float av[8] = {v0.x, v0.y, v0.z, v0.w, v1.x, v1.y, v1.z, v1.w};
#pragma unroll
        for (int r = 0; r < 4; ++r)
#pragma unroll
            for (int j = 0; j < 8; ++j) acc[r][j] += brs[r][t] * av[j];
    }
#pragma unroll
    for (int r = 0; r < 4; ++r) {
        union { unsigned short us[8]; uint4 v; } u;
#pragma unroll
        for (int j = 0; j < 8; ++j) u.us[j] = f2bf(acc[r][j]);
        *(uint4*)(Wb + (size_t)(nb + r) * K_DIM + k0) = u.v;
    }
}

// --- gemm: 256x256 tile, BK=64, 8 waves, 4-phase counted-vmcnt schedule -----
__global__ __launch_bounds__(512, 2) void gemm_kernel(
    const unsigned short* __restrict__ A,   // [8192][4096] bf16
    const unsigned short* __restrict__ B,   // [4096][4096] bf16 (W')
    const float* __restrict__ bvec, const float* __restrict__ lbvec,
    float* __restrict__ C) {
    const int tid = threadIdx.x;
    const int lane = tid & 63;
    const int wid = tid >> 6;        // 0..7
    const int wr = wid >> 2;         // 0..1  M-half (128 rows)
    const int wc = wid & 3;          // 0..3  N-quarter (64 cols)

    // XCD-column-resident mapping: XCD = bid&7 owns ntiles {2x, 2x+1};
    // walks mtiles.
    const int bid = blockIdx.x;
    const int ntile = (bid & 7) * 2 + ((bid >> 3) & 1);  // 0..15
    const int mtile = bid >> 4;                          // 0..31
    const int m0 = mtile * 256, n0 = ntile * 256;

    __shared__ __align__(16) unsigned short ldsA[2 * 2 * 128 * 64];  // 64 KiB
    __shared__ __align__(16) unsigned short ldsB[2 * 2 * 128 * 64];  // 64 KiB

    // --- staging (write side): linear LDS dest, inverse-swizzled global src
    const int lr8 = lane >> 3;             // 0..7
    const int cch = (lane & 7) ^ lr8;      // swizzled 16B-chunk index
    const unsigned short* aSb = A + (size_t)(m0 + lr8) * K_DIM + cch * 8;
    const unsigned short* bSb = B + (size_t)(n0 + lr8) * K_DIM + cch * 8;

    auto stageA = [&](int par_, int h, int kt) {
#pragma unroll
        for (int s = 0; s < 2; ++s) {
            const int j = wid * 2 + s;
            const unsigned short* g = aSb + (size_t)(h * 128 + j * 8) * K_DIM + kt * 64;
            __builtin_amdgcn_global_load_lds(
                (const __attribute__((address_space(1))) void*)g,
                (__attribute__((address_space(3))) void*)(ldsA + (par_ * 2 + h) * 8192 + j * 512),
                16, 0, 0);
        }
    };
    auto stageB = [&](int par_, int h, int kt) {
#pragma unroll
        for (int s = 0; s < 2; ++s) {
            const int j = wid * 2 + s;
            const unsigned short* g = bSb + (size_t)(h * 128 + j * 8) * K_DIM + kt * 64;
            __builtin_amdgcn_global_load_lds(
                (const __attribute__((address_space(1))) void*)g,
                (__attribute__((address_space(3))) void*)(ldsB + (par_ * 2 + h) * 8192 + j * 512),
                16, 0, 0);
        }
    };

    // --- read side (T2 swizzle on the byte address) ---
    const int rowByte = (lane & 15) * 128;
    const int swz = (lane & 7) << 4;
    const int kc0 = (0 * 64 + (lane >> 4) * 16) ^ swz;
    const int kc1 = (1 * 64 + (lane >> 4) * 16) ^ swz;
    const int baseBoff = (wc & 1) * 4096;  // 64-row sub-block within 128-row half

    auto readA = [&](int par_, int mf, int kk) -> bf16x8 {
        const char* p = (const char*)(ldsA + (par_ * 2 + wr) * 8192 + mf * 1024) +
                        rowByte + (kk ? kc1 : kc0);
        return *(const bf16x8*)p;
    };
    auto readB = [&](int par_, int nf, int kk) -> bf16x8 {
        const char* p = (const char*)(ldsB + (par_ * 2 + (wc >> 1)) * 8192 + baseBoff + nf * 1024) +
                        rowByte + (kk ? kc1 : kc0);
        return *(const bf16x8*)p;
    };

    f32x4 acc[8][4] = {};
    bf16x8 a[4][2], b[4][2];

    auto mfmaQ = [&](int qm, int qn) {   // 16 MFMA: 4 mf x 2 nf x 2 kk
#pragma unroll
        for (int i = 0; i < 4; ++i)
#pragma unroll
            for (int jn = 0; jn < 2; ++jn)
#pragma unroll
                for (int kk = 0; kk < 2; ++kk)
                    acc[qm * 4 + i][qn * 2 + jn] = __builtin_amdgcn_mfma_f32_16x16x32_bf16(
                        a[i][kk], b[qn * 2 + jn][kk], acc[qm * 4 + i][qn * 2 + jn], 0, 0, 0);
    };

    // --- prologue: stage t0,t1 (16 loads); drain t0; PUBLISH (barrier);
    //     then pre-read b0-1(t0) ---
    stageB(0, 0, 0); stageB(0, 1, 0); stageA(0, 0, 0); stageA(0, 1, 0);
    stageB(1, 0, 1); stageB(1, 1, 1); stageA(1, 0, 1); stageA(1, 1, 1);
    WAITV8();
    BARRIER();
#pragma unroll
    for (int nf = 0; nf < 2; ++nf)
#pragma unroll
        for (int kk = 0; kk < 2; ++kk) b[nf][kk] = readB(0, nf, kk);

    // Per K-tile: p1=8(a0-3) p2=4(b2-3) p3=8(a4-7)+stageB+drain(t+1) p4=stageA+4(b0-1 t+1)
#define KTILE(kt, par)                                                          \
    {                                                                           \
        /* p1: read a0-3; MFMA Q(0,0) (b0-1 already in regs) */                 \
        _Pragma("unroll") for (int i = 0; i < 4; ++i)                           \
            _Pragma("unroll") for (int kk = 0; kk < 2; ++kk)                    \
                a[i][kk] = readA(par, i, kk);                                    \
        BARRIER();                                                              \
        __builtin_amdgcn_s_setprio(1); mfmaQ(0, 0); __builtin_amdgcn_s_setprio(0); \
        BARRIER();                                                              \
        /* p2: read b2-3; MFMA Q(0,1) */                                        \
        _Pragma("unroll") for (int nf = 2; nf < 4; ++nf)                        \
            _Pragma("unroll") for (int kk = 0; kk < 2; ++kk)                    \
                b[nf][kk] = readB(par, nf, kk);                                  \
        BARRIER();                                                              \
        __builtin_amdgcn_s_setprio(1); mfmaQ(0, 1); __builtin_amdgcn_s_setprio(0); \
        BARRIER();                                                              \
        /* p3: read a4-7; stage B(t+2); drain t+1 (vmcnt4 / 0 at tail);         \
           closing barrier PUBLISHES t+1 */                                     \
        _Pragma("unroll") for (int i = 0; i < 4; ++i)                           \
            _Pragma("unroll") for (int kk = 0; kk < 2; ++kk)                    \
                a[i][kk] = readA(par, 4 + i, kk);                                \
        if ((kt) + 2 < NT) { stageB(par, 0, (kt) + 2); stageB(par, 1, (kt) + 2); WAITV4(); } \
        else { WAITV0(); }                                                      \
        BARRIER();                                                              \
        __builtin_amdgcn_s_setprio(1); mfmaQ(1, 0); __builtin_amdgcn_s_setprio(0); \
        BARRIER();                                                              \
        /* p4: stage A(t+2); pre-read b0-1(t+1) [published at p3]; MFMA Q(1,1) */ \
        if ((kt) + 2 < NT) { stageA(par, 0, (kt) + 2); stageA(par, 1, (kt) + 2); } \
        if ((kt) + 1 < NT) {                                                    \
            _Pragma("unroll") for (int nf = 0; nf < 2; ++nf)                    \
                _Pragma("unroll") for (int kk = 0; kk < 2; ++kk)                \
                    b[nf][kk] = readB((par) ^ 1, nf, kk);                        \
        }                                                                       \
        BARRIER();                                                              \
        __builtin_amdgcn_s_setprio(1); mfmaQ(1, 1); __builtin_amdgcn_s_setprio(0); \
        BARRIER();                                                              \
    }

#pragma unroll 1
    for (int kt = 0; kt < NT; kt += 2) {
        KTILE(kt, 0);
        KTILE(kt + 1, 1);
    }
#undef KTILE

    // --- epilogue: C = acc + (b + lora_bias); NON-TEMPORAL stores so the
    //     128MB C stream doesn't evict A/B panels from L2/L3. ---
#pragma unroll
    for (int nf = 0; nf < 4; ++nf) {
        const int gc = n0 + wc * 64 + nf * 16 + (lane & 15);
        const float bv = bvec[gc] + lbvec[gc];
#pragma unroll
        for (int mf = 0; mf < 8; ++mf) {
            const int gr0 = m0 + wr * 128 + mf * 16 + (lane >> 4) * 4;
            f32x4 v = acc[mf][nf];
#pragma unroll
            for (int j = 0; j < 4; ++j)
                __builtin_nontemporal_store(v[j] + bv, &C[(size_t)(gr0 + j) * N_DIM + gc]);
        }
    }
}

// --- Fallback: naive fp32 (only if ws too small) ----------------------------
__global__ __launch_bounds__(256) void naive_kernel(
    const float* __restrict__ x, const float* __restrict__ W,
    const float* __restrict__ b, const float* __restrict__ lA,
    const float* __restrict__ lB, const float* __restrict__ lb,
    float* __restrict__ out) {
    __shared__ float xs[K_DIM];
    __shared__ float ts[16];
    const int m = blockIdx.x;
    const int tid = threadIdx.x;
    for (int k = tid; k < K_DIM; k += 256) xs[k] = x[(size_t)m * K_DIM + k];
    if (tid < 16) ts[tid] = 0.f;
    __syncthreads();
    float part[16] = {};
    for (int k = tid * 16; k < tid * 16 + 16; ++k) {
        float xv = xs[k];
#pragma unroll
        for (int r = 0; r < 16; ++r) part[r] += xv * lA[(size_t)r * K_DIM + k];
    }
#pragma unroll
    for (int r = 0; r < 16; ++r) atomicAdd(&ts[r], part[r]);
    __syncthreads();
    const int n = blockIdx.y * 256 + tid;
    float acc = b[n] + lb[n];
#pragma unroll
    for (int r = 0; r < 16; ++r) acc += ts[r] * lB[(size_t)n * 16 + r];
    const float* wrow = W + (size_t)n * K_DIM;
    for (int k = 0; k < K_DIM; ++k) acc += xs[k] * wrow[k];
    out[(size_t)m * N_DIM + n] = acc;
}

// ---------------------------------------------------------------------------
extern "C" void kernel_launch(void* const* d_in, const int* in_sizes, int n_in,
                              void* d_out, int out_size, void* d_ws, size_t ws_size,
                              hipStream_t stream) {
    const float* x  = (const float*)d_in[0];
    const float* W  = (const float*)d_in[1];
    const float* b  = (const float*)d_in[2];
    const float* lA = (const float*)d_in[3];
    const float* lB = (const float*)d_in[4];
    const float* lb = (const float*)d_in[5];
    float* out = (float*)d_out;

    const size_t xb_bytes = (size_t)M_DIM * K_DIM * 2;  // 64 MiB
    const size_t wb_bytes = (size_t)N_DIM * K_DIM * 2;  // 32 MiB

    if (ws_size >= xb_bytes + wb_bytes) {
        unsigned short* xb = (unsigned short*)d_ws;
        unsigned short* wb = (unsigned short*)((char*)d_ws + xb_bytes);

        conv_x_kernel<<<(M_DIM * K_DIM) / (256 * 8), 256, 0, stream>>>(x, xb);
        conv_w_kernel<<<N_DIM / 4, 512, 0, stream>>>(W, lA, lB, wb);

        gemm_kernel<<<(M_DIM / 256) * (N_DIM / 256), 512, 0, stream>>>(xb, wb, b, lb, out);
    } else {
        dim3 grid(M_DIM, N_DIM / 256);
        naive_kernel<<<grid, 256, 0, stream>>>(x, W, b, lA, lB, lb, out);
    }
}